// Round 1
// baseline (110.357 us; speedup 1.0000x reference)
//
#include <hip/hip_runtime.h>
#include <hip/hip_bf16.h>

// Problem constants
#define B_   256
#define N_   64
#define D_   128
#define E_   8
#define T_   80
#define H_   256   // 2*D
#define O_   160   // T*2
#define NTOK 63    // tokens 1..63 used

typedef __bf16 bf16x8 __attribute__((ext_vector_type(8)));
typedef float  f32x4  __attribute__((ext_vector_type(4)));
typedef unsigned short u16x8 __attribute__((ext_vector_type(8)));
typedef unsigned short u16x4 __attribute__((ext_vector_type(4)));

struct Route { int e0, e1; float g0, g1; };

__device__ __forceinline__ unsigned short f2bf(float f) {
    unsigned int u = __builtin_bit_cast(unsigned int, f);
    u += 0x7FFFu + ((u >> 16) & 1u);   // round-to-nearest-even
    return (unsigned short)(u >> 16);
}

// ---------------- Kernel 1: weight cast + transpose ----------------
// w1 (E,D,H) f32 -> w1t (E,H,D) bf16 ; w2 (E,H,O) f32 -> w2t (E,O,H) bf16
__global__ void prep_w(const float* __restrict__ w1, const float* __restrict__ w2,
                       unsigned short* __restrict__ w1t, unsigned short* __restrict__ w2t) {
    int idx = blockIdx.x * 256 + threadIdx.x;
    if (idx < E_ * H_ * D_) {
        int d = idx & (D_ - 1);
        int h = (idx >> 7) & (H_ - 1);
        int e = idx >> 15;
        w1t[idx] = f2bf(w1[((size_t)e * D_ + d) * H_ + h]);
    }
    if (idx < E_ * O_ * H_) {
        int h = idx & (H_ - 1);
        int rest = idx >> 8;
        int o = rest % O_;
        int e = rest / O_;
        w2t[idx] = f2bf(w2[((size_t)e * H_ + h) * O_ + o]);
    }
}

// ---------------- Kernel 2: router (pool -> softmax -> top2) ----------------
__global__ void router_kernel(const float* __restrict__ x,
                              const float* __restrict__ rw,
                              const float* __restrict__ rb,
                              Route* __restrict__ rt) {
    int b = blockIdx.x;
    int lane = threadIdx.x;            // 64 threads = 1 wave
    __shared__ float pooled[D_];
    __shared__ float logits[E_];
    float s0 = 0.f, s1 = 0.f;
    const float* xb = x + (size_t)b * N_ * D_;
    for (int n = 1; n < N_; ++n) {
        s0 += xb[n * D_ + lane];
        s1 += xb[n * D_ + lane + 64];
    }
    pooled[lane]      = s0 * (1.f / 63.f);
    pooled[lane + 64] = s1 * (1.f / 63.f);
    __syncthreads();
    if (lane < E_) {
        float acc = rb[lane];
        for (int d = 0; d < D_; ++d) acc += pooled[d] * rw[d * E_ + lane];
        logits[lane] = acc;
    }
    __syncthreads();
    if (lane == 0) {
        float mx = logits[0];
        for (int e = 1; e < E_; ++e) mx = fmaxf(mx, logits[e]);
        float p[E_]; float den = 0.f;
        for (int e = 0; e < E_; ++e) { p[e] = expf(logits[e] - mx); den += p[e]; }
        float inv = 1.f / den;
        for (int e = 0; e < E_; ++e) p[e] *= inv;
        int i0 = 0;
        for (int e = 1; e < E_; ++e) if (p[e] > p[i0]) i0 = e;   // first max on ties
        int i1 = (i0 == 0) ? 1 : 0;
        for (int e = 0; e < E_; ++e) if (e != i0 && p[e] > p[i1]) i1 = e;
        Route r; r.e0 = i0; r.e1 = i1; r.g0 = p[i0]; r.g1 = p[i1];
        rt[b] = r;
    }
}

// ---------------- Kernel 3: main MoE (top-2 experts, bf16 MFMA) ----------------
// grid = (2 token-halves, B). Block = 256 threads (4 waves).
// Per block: stage xa (32 tokens x 128) bf16 in swizzled LDS; for each of the
// batch's top-2 experts: h = relu(xa@w1+b1)*gate -> swizzled LDS bf16;
// acc2 += h@w2 across both experts; single fp32 store of acc2 + gated b2.
__global__ __launch_bounds__(256)
void moe_main(const float* __restrict__ x,
              const float* __restrict__ b1,
              const float* __restrict__ b2,
              const unsigned short* __restrict__ w1t,
              const unsigned short* __restrict__ w2t,
              const Route* __restrict__ rt,
              float* __restrict__ out) {
    const int half = blockIdx.x;      // 0,1
    const int b    = blockIdx.y;      // 0..255
    const int m0   = half * 32;
    const int t    = threadIdx.x;
    const int wv   = t >> 6;          // wave 0..3
    const int lane = t & 63;
    const int q    = lane >> 4;       // quad 0..3
    const int r16  = lane & 15;

    __shared__ unsigned short xa_lds[32 * 128];  // 8 KiB, XOR-swizzled rows
    __shared__ unsigned short h_lds[32 * 256];   // 16 KiB, XOR-swizzled rows

    // ---- stage xa (f32 -> bf16, swizzled) ----
    {
        int row  = t >> 3;            // 0..31
        int col0 = (t & 7) * 16;      // 0..112
        int n = m0 + row;             // output token index (x token = 1+n)
        bool valid = (n < NTOK);
        const float* src = x + ((size_t)b * N_ + (1 + n)) * D_ + col0;
        #pragma unroll
        for (int c = 0; c < 4; ++c) {
            float4 v;
            if (valid) v = *(const float4*)(src + c * 4);
            else       v = make_float4(0.f, 0.f, 0.f, 0.f);
            u16x4 h4;
            h4[0] = f2bf(v.x); h4[1] = f2bf(v.y); h4[2] = f2bf(v.z); h4[3] = f2bf(v.w);
            int col = col0 + c * 4;
            *(u16x4*)&xa_lds[row * 128 + (col ^ ((row & 7) << 3))] = h4;
        }
    }

    Route rr = rt[b];
    const f32x4 z4 = {0.f, 0.f, 0.f, 0.f};
    f32x4 acc2[2][3];
    #pragma unroll
    for (int mt = 0; mt < 2; ++mt)
        #pragma unroll
        for (int j = 0; j < 3; ++j) acc2[mt][j] = z4;

    __syncthreads();

    #pragma unroll
    for (int s = 0; s < 2; ++s) {
        const int   e = s ? rr.e1 : rr.e0;
        const float g = s ? rr.g1 : rr.g0;
        const unsigned short* w1e = w1t + (size_t)e * H_ * D_;

        // ---- layer 1: acc1[2][4] = xa(32x128) @ w1e(128x256-cols of this wave) ----
        f32x4 acc1[2][4];
        #pragma unroll
        for (int mt = 0; mt < 2; ++mt)
            #pragma unroll
            for (int nt = 0; nt < 4; ++nt) acc1[mt][nt] = z4;

        #pragma unroll
        for (int ks = 0; ks < 4; ++ks) {
            int col0 = ks * 32 + q * 8;
            int row0 = r16, row1 = 16 + r16;
            bf16x8 a0 = __builtin_bit_cast(bf16x8,
                *(const u16x8*)&xa_lds[row0 * 128 + (col0 ^ ((row0 & 7) << 3))]);
            bf16x8 a1 = __builtin_bit_cast(bf16x8,
                *(const u16x8*)&xa_lds[row1 * 128 + (col0 ^ ((row1 & 7) << 3))]);
            #pragma unroll
            for (int nt = 0; nt < 4; ++nt) {
                int col = wv * 64 + nt * 16 + r16;
                bf16x8 bb = __builtin_bit_cast(bf16x8,
                    *(const u16x8*)(w1e + (size_t)col * D_ + ks * 32 + q * 8));
                acc1[0][nt] = __builtin_amdgcn_mfma_f32_16x16x32_bf16(a0, bb, acc1[0][nt], 0, 0, 0);
                acc1[1][nt] = __builtin_amdgcn_mfma_f32_16x16x32_bf16(a1, bb, acc1[1][nt], 0, 0, 0);
            }
        }

        // slot 1 must wait until all waves finished reading h_lds of slot 0
        if (s == 1) __syncthreads();

        // ---- relu + bias + gate, write h to swizzled LDS as bf16 ----
        float b1v[4];
        #pragma unroll
        for (int nt = 0; nt < 4; ++nt) b1v[nt] = b1[e * H_ + wv * 64 + nt * 16 + r16];
        #pragma unroll
        for (int mt = 0; mt < 2; ++mt)
            #pragma unroll
            for (int nt = 0; nt < 4; ++nt) {
                int col = wv * 64 + nt * 16 + r16;
                #pragma unroll
                for (int rg = 0; rg < 4; ++rg) {
                    int row = mt * 16 + q * 4 + rg;
                    float v = acc1[mt][nt][rg] + b1v[nt];
                    v = fmaxf(v, 0.f) * g;
                    h_lds[row * 256 + (col ^ ((row & 7) << 3))] = f2bf(v);
                }
            }
        __syncthreads();

        // ---- layer 2: acc2 += h(32x256) @ w2e(256 x wave's o-cols) ----
        const unsigned short* w2e = w2t + (size_t)e * O_ * H_;
        #pragma unroll
        for (int ks = 0; ks < 8; ++ks) {
            int col0 = ks * 32 + q * 8;
            int row0 = r16, row1 = 16 + r16;
            bf16x8 a0 = __builtin_bit_cast(bf16x8,
                *(const u16x8*)&h_lds[row0 * 256 + (col0 ^ ((row0 & 7) << 3))]);
            bf16x8 a1 = __builtin_bit_cast(bf16x8,
                *(const u16x8*)&h_lds[row1 * 256 + (col0 ^ ((row1 & 7) << 3))]);
            #pragma unroll
            for (int j = 0; j < 3; ++j) {
                int nt2 = wv + j * 4;
                if (nt2 < 10) {
                    int col = nt2 * 16 + r16;
                    bf16x8 bb = __builtin_bit_cast(bf16x8,
                        *(const u16x8*)(w2e + (size_t)col * H_ + col0));
                    acc2[0][j] = __builtin_amdgcn_mfma_f32_16x16x32_bf16(a0, bb, acc2[0][j], 0, 0, 0);
                    acc2[1][j] = __builtin_amdgcn_mfma_f32_16x16x32_bf16(a1, bb, acc2[1][j], 0, 0, 0);
                }
            }
        }
    }

    // ---- epilogue: add gated b2, store fp32 ----
    #pragma unroll
    for (int j = 0; j < 3; ++j) {
        int nt2 = wv + j * 4;
        if (nt2 < 10) {
            int col = nt2 * 16 + r16;
            float bias = rr.g0 * b2[rr.e0 * O_ + col] + rr.g1 * b2[rr.e1 * O_ + col];
            #pragma unroll
            for (int mt = 0; mt < 2; ++mt)
                #pragma unroll
                for (int rg = 0; rg < 4; ++rg) {
                    int row = mt * 16 + q * 4 + rg;
                    int n = m0 + row;
                    if (n < NTOK)
                        out[((size_t)b * NTOK + n) * O_ + col] = acc2[mt][j][rg] + bias;
                }
        }
    }
}

// ---------------- launch ----------------
extern "C" void kernel_launch(void* const* d_in, const int* in_sizes, int n_in,
                              void* d_out, int out_size, void* d_ws, size_t ws_size,
                              hipStream_t stream) {
    const float* x  = (const float*)d_in[0];
    const float* rw = (const float*)d_in[1];
    const float* rb = (const float*)d_in[2];
    const float* w1 = (const float*)d_in[3];
    const float* b1 = (const float*)d_in[4];
    const float* w2 = (const float*)d_in[5];
    const float* b2 = (const float*)d_in[6];
    float* out = (float*)d_out;

    unsigned short* w1t = (unsigned short*)d_ws;            // E*H*D bf16 = 512 KiB
    unsigned short* w2t = w1t + (size_t)E_ * H_ * D_;       // E*O*H bf16 = 640 KiB
    Route* rt = (Route*)(w2t + (size_t)E_ * O_ * H_);       // 4 KiB

    prep_w<<<1280, 256, 0, stream>>>(w1, w2, w1t, w2t);
    router_kernel<<<B_, 64, 0, stream>>>(x, rw, rb, rt);
    moe_main<<<dim3(2, B_), 256, 0, stream>>>(x, b1, b2, w1t, w2t, rt, out);
}

// Round 2
// 99.342 us; speedup vs baseline: 1.1109x; 1.1109x over previous
//
#include <hip/hip_runtime.h>
#include <hip/hip_bf16.h>

// Problem constants
#define B_   256
#define N_   64
#define D_   128
#define E_   8
#define T_   80
#define H_   256   // 2*D
#define O_   160   // T*2
#define NTOK 63    // tokens 1..63 used

typedef __bf16 bf16x8 __attribute__((ext_vector_type(8)));
typedef float  f32x4  __attribute__((ext_vector_type(4)));
typedef unsigned short u16x8 __attribute__((ext_vector_type(8)));
typedef unsigned short u16x4 __attribute__((ext_vector_type(4)));

__device__ __forceinline__ unsigned short f2bf(float f) {
    unsigned int u = __builtin_bit_cast(unsigned int, f);
    u += 0x7FFFu + ((u >> 16) & 1u);   // round-to-nearest-even
    return (unsigned short)(u >> 16);
}

// ---------------- Kernel 1: weight cast + transpose (tiled, coalesced) ----
// w1 (E,D,H) f32 -> w1t (E,H,D) bf16 ; w2 (E,H,O) f32 -> w2t (E,O,H) bf16
// 32x32 tiles through padded LDS. bid<256 -> w1 tiles, else w2 tiles.
__global__ __launch_bounds__(256)
void prep_w(const float* __restrict__ w1, const float* __restrict__ w2,
            unsigned short* __restrict__ w1t, unsigned short* __restrict__ w2t) {
    __shared__ float tile[32][33];
    const int bid = blockIdx.x;
    const int t = threadIdx.x;
    const int r  = t >> 3;          // 0..31 (read row)
    const int c4 = (t & 7) * 4;     // 0..28 (read col base)

    const float* src; unsigned short* dst;
    int src_ld, dst_ld;
    size_t soff, doff;
    if (bid < 256) {                 // w1: per-e (128 x 256) -> (256 x 128)
        int e = bid >> 5, rest = bid & 31;
        int dt = rest >> 3, ht = rest & 7;        // d-tile 0..3, h-tile 0..7
        soff = ((size_t)e * 128 + dt * 32) * 256 + ht * 32; src_ld = 256;
        doff = ((size_t)e * 256 + ht * 32) * 128 + dt * 32; dst_ld = 128;
        src = w1; dst = w1t;
    } else {                         // w2: per-e (256 x 160) -> (160 x 256)
        int id = bid - 256;
        int e = id / 40, rest = id % 40;
        int ht = rest / 5, ot = rest % 5;         // h-tile 0..7, o-tile 0..4
        soff = ((size_t)e * 256 + ht * 32) * 160 + ot * 32; src_ld = 160;
        doff = ((size_t)e * 160 + ot * 32) * 256 + ht * 32; dst_ld = 256;
        src = w2; dst = w2t;
    }
    float4 v = *(const float4*)(src + soff + (size_t)r * src_ld + c4);
    tile[r][c4 + 0] = v.x; tile[r][c4 + 1] = v.y;
    tile[r][c4 + 2] = v.z; tile[r][c4 + 3] = v.w;
    __syncthreads();
    const int c  = t >> 3;          // transposed row = source col
    const int r4 = (t & 7) * 4;     // transposed col base = source row
    u16x4 h4;
    h4[0] = f2bf(tile[r4 + 0][c]); h4[1] = f2bf(tile[r4 + 1][c]);
    h4[2] = f2bf(tile[r4 + 2][c]); h4[3] = f2bf(tile[r4 + 3][c]);
    *(u16x4*)(dst + doff + (size_t)c * dst_ld + r4) = h4;
}

// ---------------- Kernel 2: fused router + top-2 MoE ----------------
// One block per batch. 512 threads = 8 waves (2 M-groups x 4 N-groups).
// Stage xa (64x128, rows 0..62 valid) to swizzled LDS while pooling in fp32;
// route in-block; then per expert: h=relu(xa@w1+b1)*g -> LDS; acc2 += h@w2.
__global__ __launch_bounds__(512)
void moe_fused(const float* __restrict__ x,
               const float* __restrict__ rw,
               const float* __restrict__ rb,
               const float* __restrict__ b1,
               const float* __restrict__ b2,
               const unsigned short* __restrict__ w1t,
               const unsigned short* __restrict__ w2t,
               float* __restrict__ out) {
    const int b    = blockIdx.x;
    const int t    = threadIdx.x;
    const int wv   = t >> 6;
    const int lane = t & 63;
    const int wvM  = wv >> 2;         // 0,1  (rows wvM*32 ..)
    const int wvN  = wv & 3;          // 0..3 (layer1 cols wvN*64 ..)
    const int q    = lane >> 4;       // 0..3
    const int r16  = lane & 15;

    __shared__ unsigned short xa_lds[64 * 128];   // 16 KiB, XOR-swizzled rows
    __shared__ unsigned short h_lds[64 * 256];    // 32 KiB, XOR-swizzled rows
    __shared__ float part[16][128];               // 8 KiB pooling partials
    __shared__ float pooled[128];
    __shared__ int   re_s[2];
    __shared__ float rg_s[2];

    // ---- stage xa (f32 -> bf16, swizzled) + fp32 pooling partials ----
    {
        const int rbase = t >> 5;        // 0..15
        const int c0    = (t & 31) * 4;  // 0..124
        float4 ps = make_float4(0.f, 0.f, 0.f, 0.f);
        const float* xb = x + ((size_t)b * N_ + 1) * D_;   // token 1 == row 0
        #pragma unroll
        for (int rr = 0; rr < 4; ++rr) {
            int row = rbase + rr * 16;
            float4 v = make_float4(0.f, 0.f, 0.f, 0.f);
            if (row < NTOK) v = *(const float4*)(xb + (size_t)row * D_ + c0);
            ps.x += v.x; ps.y += v.y; ps.z += v.z; ps.w += v.w;
            u16x4 h4;
            h4[0] = f2bf(v.x); h4[1] = f2bf(v.y);
            h4[2] = f2bf(v.z); h4[3] = f2bf(v.w);
            *(u16x4*)&xa_lds[row * 128 + (c0 ^ ((row & 7) << 3))] = h4;
        }
        *(float4*)&part[rbase][c0] = ps;   // unique writer per slot
    }
    __syncthreads();

    // ---- pooled mean (fp32) ----
    if (t < 128) {
        float s = 0.f;
        #pragma unroll
        for (int i = 0; i < 16; ++i) s += part[i][t];
        pooled[t] = s * (1.f / 63.f);
    }
    __syncthreads();

    // ---- routing: logits -> softmax -> top-2, all in wave 0 ----
    if (t < 64) {
        int e  = lane >> 3;        // 0..7
        int dg = lane & 7;         // dim group, 16 dims each
        float p = 0.f;
        #pragma unroll
        for (int i = 0; i < 16; ++i)
            p += pooled[dg * 16 + i] * rw[(dg * 16 + i) * E_ + e];
        p += __shfl_xor(p, 1); p += __shfl_xor(p, 2); p += __shfl_xor(p, 4);
        float lg[E_];
        #pragma unroll
        for (int e2 = 0; e2 < E_; ++e2) lg[e2] = __shfl(p, e2 * 8) + rb[e2];
        if (lane == 0) {
            float mx = lg[0];
            for (int i = 1; i < E_; ++i) mx = fmaxf(mx, lg[i]);
            float pr[E_]; float den = 0.f;
            for (int i = 0; i < E_; ++i) { pr[i] = expf(lg[i] - mx); den += pr[i]; }
            int i0 = 0;
            for (int i = 1; i < E_; ++i) if (pr[i] > pr[i0]) i0 = i;  // first on tie
            int i1 = (i0 == 0) ? 1 : 0;
            for (int i = 0; i < E_; ++i) if (i != i0 && pr[i] > pr[i1]) i1 = i;
            float inv = 1.f / den;
            re_s[0] = i0; re_s[1] = i1;
            rg_s[0] = pr[i0] * inv; rg_s[1] = pr[i1] * inv;
        }
    }
    __syncthreads();

    const int   e0 = re_s[0], e1 = re_s[1];
    const float g0 = rg_s[0], g1 = rg_s[1];

    const f32x4 z4 = {0.f, 0.f, 0.f, 0.f};
    f32x4 acc2[2][3];
    #pragma unroll
    for (int mt = 0; mt < 2; ++mt)
        #pragma unroll
        for (int j = 0; j < 3; ++j) acc2[mt][j] = z4;

    #pragma unroll
    for (int s = 0; s < 2; ++s) {
        const int   e = s ? e1 : e0;
        const float g = s ? g1 : g0;
        const unsigned short* w1e = w1t + (size_t)e * H_ * D_;

        // ---- layer 1: acc1 = xa(rows wvM*32+32) @ w1e(cols wvN*64+64) ----
        f32x4 acc1[2][4];
        #pragma unroll
        for (int mt = 0; mt < 2; ++mt)
            #pragma unroll
            for (int nt = 0; nt < 4; ++nt) acc1[mt][nt] = z4;

        const int row0 = wvM * 32 + r16;
        const int row1 = wvM * 32 + 16 + r16;
        #pragma unroll
        for (int ks = 0; ks < 4; ++ks) {
            int col0k = ks * 32 + q * 8;
            bf16x8 a0 = __builtin_bit_cast(bf16x8,
                *(const u16x8*)&xa_lds[row0 * 128 + (col0k ^ ((row0 & 7) << 3))]);
            bf16x8 a1 = __builtin_bit_cast(bf16x8,
                *(const u16x8*)&xa_lds[row1 * 128 + (col0k ^ ((row1 & 7) << 3))]);
            #pragma unroll
            for (int nt = 0; nt < 4; ++nt) {
                int col = wvN * 64 + nt * 16 + r16;
                bf16x8 bb = __builtin_bit_cast(bf16x8,
                    *(const u16x8*)(w1e + (size_t)col * D_ + col0k));
                acc1[0][nt] = __builtin_amdgcn_mfma_f32_16x16x32_bf16(a0, bb, acc1[0][nt], 0, 0, 0);
                acc1[1][nt] = __builtin_amdgcn_mfma_f32_16x16x32_bf16(a1, bb, acc1[1][nt], 0, 0, 0);
            }
        }

        // slot 1 must wait until all waves finished reading h_lds of slot 0
        if (s == 1) __syncthreads();

        // ---- relu + bias + gate -> swizzled LDS bf16 ----
        float b1v[4];
        #pragma unroll
        for (int nt = 0; nt < 4; ++nt) b1v[nt] = b1[e * H_ + wvN * 64 + nt * 16 + r16];
        #pragma unroll
        for (int mt = 0; mt < 2; ++mt)
            #pragma unroll
            for (int nt = 0; nt < 4; ++nt) {
                int col = wvN * 64 + nt * 16 + r16;
                #pragma unroll
                for (int rg = 0; rg < 4; ++rg) {
                    int row = wvM * 32 + mt * 16 + q * 4 + rg;
                    float v = acc1[mt][nt][rg] + b1v[nt];
                    v = fmaxf(v, 0.f) * g;
                    h_lds[row * 256 + (col ^ ((row & 7) << 3))] = f2bf(v);
                }
            }
        __syncthreads();

        // ---- layer 2: acc2 += h(rows wvM*32+32, K=256) @ w2e(10 col-tiles) ----
        const unsigned short* w2e = w2t + (size_t)e * O_ * H_;
        #pragma unroll
        for (int ks = 0; ks < 8; ++ks) {
            int col0k = ks * 32 + q * 8;
            bf16x8 a0 = __builtin_bit_cast(bf16x8,
                *(const u16x8*)&h_lds[row0 * 256 + (col0k ^ ((row0 & 7) << 3))]);
            bf16x8 a1 = __builtin_bit_cast(bf16x8,
                *(const u16x8*)&h_lds[row1 * 256 + (col0k ^ ((row1 & 7) << 3))]);
            #pragma unroll
            for (int j = 0; j < 3; ++j) {
                int nt2 = wvN + j * 4;
                if (nt2 < 10) {
                    int col = nt2 * 16 + r16;
                    bf16x8 bb = __builtin_bit_cast(bf16x8,
                        *(const u16x8*)(w2e + (size_t)col * H_ + col0k));
                    acc2[0][j] = __builtin_amdgcn_mfma_f32_16x16x32_bf16(a0, bb, acc2[0][j], 0, 0, 0);
                    acc2[1][j] = __builtin_amdgcn_mfma_f32_16x16x32_bf16(a1, bb, acc2[1][j], 0, 0, 0);
                }
            }
        }
    }

    // ---- epilogue: add gated b2, store fp32 ----
    #pragma unroll
    for (int j = 0; j < 3; ++j) {
        int nt2 = wvN + j * 4;
        if (nt2 < 10) {
            int col = nt2 * 16 + r16;
            float bias = g0 * b2[e0 * O_ + col] + g1 * b2[e1 * O_ + col];
            #pragma unroll
            for (int mt = 0; mt < 2; ++mt)
                #pragma unroll
                for (int rg = 0; rg < 4; ++rg) {
                    int n = wvM * 32 + mt * 16 + q * 4 + rg;
                    if (n < NTOK)
                        out[((size_t)b * NTOK + n) * O_ + col] = acc2[mt][j][rg] + bias;
                }
        }
    }
}

// ---------------- launch ----------------
extern "C" void kernel_launch(void* const* d_in, const int* in_sizes, int n_in,
                              void* d_out, int out_size, void* d_ws, size_t ws_size,
                              hipStream_t stream) {
    const float* x  = (const float*)d_in[0];
    const float* rw = (const float*)d_in[1];
    const float* rb = (const float*)d_in[2];
    const float* w1 = (const float*)d_in[3];
    const float* b1 = (const float*)d_in[4];
    const float* w2 = (const float*)d_in[5];
    const float* b2 = (const float*)d_in[6];
    float* out = (float*)d_out;

    unsigned short* w1t = (unsigned short*)d_ws;            // E*H*D bf16 = 512 KiB
    unsigned short* w2t = w1t + (size_t)E_ * H_ * D_;       // E*O*H bf16 = 640 KiB

    prep_w<<<576, 256, 0, stream>>>(w1, w2, w1t, w2t);
    moe_fused<<<B_, 512, 0, stream>>>(x, rw, rb, b1, b2, w1t, w2t, out);
}